// Round 4
// baseline (15647.997 us; speedup 1.0000x reference)
//
#include <hip/hip_runtime.h>
#include <hip/hip_fp16.h>

#define B_ 64
#define T_ 512
#define I_ 128
#define H_ 512

typedef _Float16 half2v __attribute__((ext_vector_type(2)));

__device__ __forceinline__ float dot2(unsigned a, unsigned b, float c) {
    return __builtin_amdgcn_fdot2(__builtin_bit_cast(half2v, a),
                                  __builtin_bit_cast(half2v, b), c, false);
}

__device__ __forceinline__ unsigned short f32_to_f16b(float f) {
    _Float16 h = (_Float16)f;
    return __builtin_bit_cast(unsigned short, h);
}

// Pin 2 uint4s (8 dwords) into the ACC register file.
#define PIN_A2(U, V)                                                       \
    asm volatile("" : "+a"((U).x), "+a"((U).y), "+a"((U).z), "+a"((U).w),  \
                      "+a"((V).x), "+a"((V).y), "+a"((V).z), "+a"((V).w))

// ---------------------------------------------------------------------------
// Kernel 1: W_hid fp32 [H,H] -> packed f16 pairs for `recurrent`.
// Consumer thread (w=t>>6, l=t&63) covers h-slots i in [0,8): h = l + 64*i,
// k-slice of wave w: pairs kp = 32w + 4g + m (g in [0,8), m = dword in uint4).
//  - VGPR part (slots i<6):  uint4 idx ((w*6+i)*8+g)*64 + l   -> dwords [0, 98304)
//  - LDS part  (slots 6,7):  uint4 idx ((w*2+ii)*8+g)*64 + l  -> dwords [98304, 131072)
// ---------------------------------------------------------------------------
__global__ void wconv(const float* __restrict__ Whid,
                      unsigned* __restrict__ Wz) {
    int p = blockIdx.x * 256 + threadIdx.x;   // dword index, 0..131071
    int m  = p & 3;
    int u4 = p >> 2;
    int l, g, w, i;
    if (u4 < 24576) {                 // VGPR part
        l = u4 & 63; g = (u4 >> 6) & 7;
        int r = u4 >> 9;              // 0..47
        w = r / 6; i = r - 6 * w;
    } else {                          // LDS part
        int q = u4 - 24576;           // 0..8191
        l = q & 63; g = (q >> 6) & 7;
        int r = q >> 9;               // 0..15
        w = r >> 1; i = 6 + (r & 1);
    }
    int h  = l + 64 * i;
    int kp = 32 * w + 4 * g + m;
    float w0 = Whid[h * H_ + 2 * kp];
    float w1 = Whid[h * H_ + 2 * kp + 1];
    half2v hw = { (_Float16)w0, (_Float16)w1 };
    Wz[p] = __builtin_bit_cast(unsigned, hw);
}

// ---------------------------------------------------------------------------
// Kernel 2: v_in[b,t,h] = x[b,t,:] @ W_in[h,:] + b_in[h]  (unchanged)
// ---------------------------------------------------------------------------
__global__ __launch_bounds__(256) void vin_gemm(const float* __restrict__ x,
                                                const float* __restrict__ Win,
                                                const float* __restrict__ bin,
                                                float* __restrict__ vin) {
    __shared__ __align__(16) unsigned xs[64 * 64];   // 16 KB
    __shared__ __align__(16) unsigned ws[64 * 64];   // 16 KB
    const int tid = threadIdx.x;
    const int m0 = blockIdx.x * 64;
    const int n0 = blockIdx.y * 64;

    #pragma unroll
    for (int r = 0; r < 8; ++r) {
        int gi = r * 256 + tid;       // 0..2047
        int row = gi >> 5;            // 0..63
        int c4 = gi & 31;             // float4 index in the 128-float row
        float4 vx = ((const float4*)(x + (size_t)(m0 + row) * I_))[c4];
        float4 vw = ((const float4*)(Win + (size_t)(n0 + row) * I_))[c4];
        int sw = (row >> 2) & 15;
        int col = 4 * ((c4 >> 1) ^ sw) + (c4 & 1) * 2;  // swizzled dword col
        half2v x01 = { (_Float16)vx.x, (_Float16)vx.y };
        half2v x23 = { (_Float16)vx.z, (_Float16)vx.w };
        half2v w01 = { (_Float16)vw.x, (_Float16)vw.y };
        half2v w23 = { (_Float16)vw.z, (_Float16)vw.w };
        xs[row * 64 + col]     = __builtin_bit_cast(unsigned, x01);
        xs[row * 64 + col + 1] = __builtin_bit_cast(unsigned, x23);
        ws[row * 64 + col]     = __builtin_bit_cast(unsigned, w01);
        ws[row * 64 + col + 1] = __builtin_bit_cast(unsigned, w23);
    }
    __syncthreads();

    const int ty = tid >> 4, tx = tid & 15;
    float acc[4][4] = {};
    #pragma unroll
    for (int kb = 0; kb < 16; ++kb) {
        uint4 a4[4], b4[4];
        #pragma unroll
        for (int i = 0; i < 4; ++i)
            a4[i] = *(const uint4*)&xs[(ty * 4 + i) * 64 + 4 * (kb ^ ty)];
        #pragma unroll
        for (int j = 0; j < 4; ++j)
            b4[j] = *(const uint4*)&ws[(tx * 4 + j) * 64 + 4 * (kb ^ tx)];
        #pragma unroll
        for (int i = 0; i < 4; ++i)
            #pragma unroll
            for (int j = 0; j < 4; ++j) {
                acc[i][j] = dot2(a4[i].x, b4[j].x, acc[i][j]);
                acc[i][j] = dot2(a4[i].y, b4[j].y, acc[i][j]);
                acc[i][j] = dot2(a4[i].z, b4[j].z, acc[i][j]);
                acc[i][j] = dot2(a4[i].w, b4[j].w, acc[i][j]);
            }
    }

    float4 bv = ((const float4*)(bin + n0))[tx];
    #pragma unroll
    for (int i = 0; i < 4; ++i) {
        int m = m0 + ty * 4 + i;
        float4 o;
        o.x = acc[i][0] + bv.x; o.y = acc[i][1] + bv.y;
        o.z = acc[i][2] + bv.z; o.w = acc[i][3] + bv.w;
        ((float4*)(vin + (size_t)m * H_ + n0))[tx] = o;
    }
}

// ---------------------------------------------------------------------------
// Kernel 3: recurrence, one block per batch, k-split by wave (R2 structure,
// 773us proven).  Changes this round:
//  - wv pinned to the ACC register file ("+a") INSIDE the step loop: if W
//    was scratch-spilled this forces cheap AGPR residency (VALU reads AGPRs
//    natively on CDNA2+); if it was already in AGPRs this is a no-op.
//  - pbuf stride 10 -> 9 with b32 ops: odd stride => 2 lanes/bank (free),
//    kills the 4.19M SQ_LDS_BANK_CONFLICT.
//  - tree reduce (shorter dependent chain), fr16 write hoisted before the
//    fire-and-forget o0/o1 stores.
//  - both barriers remain lgkm-only (no vmcnt drain in the loop).
// ---------------------------------------------------------------------------
__global__ __launch_bounds__(512, 2)
__attribute__((amdgpu_waves_per_eu(2, 2)))
void recurrent(
        const uint4* __restrict__ Wz4,
        const float* __restrict__ vin,
        const float* __restrict__ init_state,
        const float* __restrict__ b_hid,
        const float* __restrict__ alpha,
        float* __restrict__ out0,
        float* __restrict__ out1) {
    __shared__ uint4 ldsW[8192];        // 128 KB : W slots 6,7
    __shared__ uint4 frbuf4[2][64];     //   2 KB : fr as f16 pairs, dbuf
    __shared__ float pbuf[8][576];      //  18 KB : partials [w][l*9+i], stride 9

    const int t = threadIdx.x;
    const int b = blockIdx.x;
    const int w = t >> 6, l = t & 63;

    // ---- W slots 0..5: 48 coalesced uint4 loads, pinned into ACC file ----
    uint4 wv[6][8];
    const uint4* wp = Wz4 + (size_t)(w * 48) * 64 + l;
    #pragma unroll
    for (int i = 0; i < 6; ++i)
        #pragma unroll
        for (int g = 0; g < 8; ++g)
            wv[i][g] = wp[(i * 8 + g) * 64];
    #pragma unroll
    for (int i = 0; i < 6; ++i)
        #pragma unroll
        for (int g = 0; g < 8; g += 2)
            PIN_A2(wv[i][g], wv[i][g + 1]);

    // ---- W slots 6,7 into LDS: 16 b128 per thread, linear ----------------
    const uint4* lsrc = Wz4 + 24576;
    #pragma unroll
    for (int kk = 0; kk < 16; ++kk) ldsW[kk * 512 + t] = lsrc[kk * 512 + t];

    // ---- init ------------------------------------------------------------
    unsigned short* fr16 = (unsigned short*)frbuf4;   // [2][512]
    float v = init_state[b * H_ + t];
    fr16[t] = f32_to_f16b(fmaxf(v, 0.0f));
    const float bh = b_hid[t];
    const float al = alpha[t];
    const float om = 1.0f - al;

    const float* vinp = vin + (size_t)b * T_ * H_ + t;
    float* o0 = out0 + (size_t)b * T_ * H_ + t;
    float* o1 = out1 + (size_t)b * T_ * H_ + t;

    const int lw0 = (w * 2) * 8 * 64 + l;     // uint4 base, slot 6
    float* prow = &pbuf[w][l * 9];            // this thread's 8 partials

    __syncthreads();

    for (int s = 0; s < T_; ++s) {
        // re-pin each iteration: W must live in ACC regs, never scratch
        #pragma unroll
        for (int i = 0; i < 6; ++i)
            #pragma unroll
            for (int g = 0; g < 8; g += 2)
                PIN_A2(wv[i][g], wv[i][g + 1]);

        const int par = s & 1;
        float vinv = vinp[(size_t)s * H_];        // early issue, used late

        const uint4* fb = &frbuf4[par][w * 8];    // wave-uniform -> broadcast
        float a0 = 0.f, a1 = 0.f, a2 = 0.f, a3 = 0.f;
        float a4 = 0.f, a5 = 0.f, a6 = 0.f, a7 = 0.f;

        #pragma unroll
        for (int g = 0; g < 8; ++g) {
            uint4 wl0 = ldsW[lw0 + g * 64];       // lane-consecutive b128
            uint4 wl1 = ldsW[lw0 + 512 + g * 64];
            uint4 f = fb[g];                      // broadcast b128
            a0 = dot2(f.x, wv[0][g].x, a0); a0 = dot2(f.y, wv[0][g].y, a0);
            a0 = dot2(f.z, wv[0][g].z, a0); a0 = dot2(f.w, wv[0][g].w, a0);
            a1 = dot2(f.x, wv[1][g].x, a1); a1 = dot2(f.y, wv[1][g].y, a1);
            a1 = dot2(f.z, wv[1][g].z, a1); a1 = dot2(f.w, wv[1][g].w, a1);
            a2 = dot2(f.x, wv[2][g].x, a2); a2 = dot2(f.y, wv[2][g].y, a2);
            a2 = dot2(f.z, wv[2][g].z, a2); a2 = dot2(f.w, wv[2][g].w, a2);
            a3 = dot2(f.x, wv[3][g].x, a3); a3 = dot2(f.y, wv[3][g].y, a3);
            a3 = dot2(f.z, wv[3][g].z, a3); a3 = dot2(f.w, wv[3][g].w, a3);
            a4 = dot2(f.x, wv[4][g].x, a4); a4 = dot2(f.y, wv[4][g].y, a4);
            a4 = dot2(f.z, wv[4][g].z, a4); a4 = dot2(f.w, wv[4][g].w, a4);
            a5 = dot2(f.x, wv[5][g].x, a5); a5 = dot2(f.y, wv[5][g].y, a5);
            a5 = dot2(f.z, wv[5][g].z, a5); a5 = dot2(f.w, wv[5][g].w, a5);
            a6 = dot2(f.x, wl0.x, a6); a6 = dot2(f.y, wl0.y, a6);
            a6 = dot2(f.z, wl0.z, a6); a6 = dot2(f.w, wl0.w, a6);
            a7 = dot2(f.x, wl1.x, a7); a7 = dot2(f.y, wl1.y, a7);
            a7 = dot2(f.z, wl1.z, a7); a7 = dot2(f.w, wl1.w, a7);
        }

        // partial writes: 8 x b32, odd stride 9 -> 2 lanes/bank (free)
        prow[0] = a0; prow[1] = a1; prow[2] = a2; prow[3] = a3;
        prow[4] = a4; prow[5] = a5; prow[6] = a6; prow[7] = a7;

        // A: partials visible.  lgkm-only barrier -- no vmcnt drain.
        asm volatile("s_waitcnt lgkmcnt(0)" ::: "memory");
        __builtin_amdgcn_s_barrier();

        // reduction: thread t reduces h = t (hl = l, hi = w); tree adds
        float p0 = pbuf[0][l * 9 + w], p1 = pbuf[1][l * 9 + w];
        float p2 = pbuf[2][l * 9 + w], p3 = pbuf[3][l * 9 + w];
        float p4 = pbuf[4][l * 9 + w], p5 = pbuf[5][l * 9 + w];
        float p6 = pbuf[6][l * 9 + w], p7 = pbuf[7][l * 9 + w];
        float sum = ((p0 + p1) + (p2 + p3)) + ((p4 + p5) + (p6 + p7));

        float vhid = sum + bh;
        float vnew = om * v + al * (vhid + vinv);
        float frn = fmaxf(vnew, 0.0f);
        fr16[(par ^ 1) * 512 + t] = f32_to_f16b(frn);   // fr first: BAR-B gate
        float vr = om * vnew + al * vhid;
        v = vnew;
        float frr = fmaxf(vr, 0.0f);

        o0[(size_t)s * H_] = frn;                 // fire-and-forget
        o1[(size_t)s * H_] = frr;

        // B: fr complete + pbuf reads retired before next-step writes.
        asm volatile("s_waitcnt lgkmcnt(0)" ::: "memory");
        __builtin_amdgcn_s_barrier();
    }
}

// ---------------------------------------------------------------------------
extern "C" void kernel_launch(void* const* d_in, const int* in_sizes, int n_in,
                              void* d_out, int out_size, void* d_ws, size_t ws_size,
                              hipStream_t stream) {
    const float* x          = (const float*)d_in[0];
    const float* init_state = (const float*)d_in[1];
    const float* W_in       = (const float*)d_in[2];
    const float* b_in       = (const float*)d_in[3];
    const float* W_hid      = (const float*)d_in[4];
    const float* b_hid      = (const float*)d_in[5];
    const float* alpha      = (const float*)d_in[6];

    float* out0 = (float*)d_out;
    float* out1 = out0 + (size_t)B_ * T_ * H_;

    char* ws = (char*)d_ws;
    float*    vin = (float*)ws;                    // 67,108,864 B
    unsigned* Wz  = (unsigned*)(ws + 67108864);    //    524,288 B

    hipLaunchKernelGGL(wconv, dim3(512), dim3(256), 0, stream,
                       W_hid, Wz);
    hipLaunchKernelGGL(vin_gemm, dim3(512, 8), dim3(256), 0, stream,
                       x, W_in, b_in, vin);
    hipLaunchKernelGGL(recurrent, dim3(64), dim3(512), 0, stream,
                       (const uint4*)Wz, vin, init_state, b_hid, alpha,
                       out0, out1);
}

// Round 5
// 1287.424 us; speedup vs baseline: 12.1545x; 12.1545x over previous
//
#include <hip/hip_runtime.h>
#include <hip/hip_fp16.h>

#define B_ 64
#define T_ 512
#define I_ 128
#define H_ 512

typedef _Float16 half2v __attribute__((ext_vector_type(2)));

__device__ __forceinline__ float dot2(unsigned a, unsigned b, float c) {
    return __builtin_amdgcn_fdot2(__builtin_bit_cast(half2v, a),
                                  __builtin_bit_cast(half2v, b), c, false);
}

__device__ __forceinline__ unsigned short f32_to_f16b(float f) {
    _Float16 h = (_Float16)f;
    return __builtin_bit_cast(unsigned short, h);
}

// Park a dword in the ACC file (one-time, init): guaranteed-assembling.
#define AWR(dst, src) \
    asm("v_accvgpr_write_b32 %0, %1" : "=a"(dst) : "v"(src))
// Fetch a dword from the ACC file (per use, volatile so it stays in-loop).
#define ARD(dst, src) \
    asm volatile("v_accvgpr_read_b32 %0, %1" : "=v"(dst) : "a"(src))

// ---------------------------------------------------------------------------
// Kernel 1: W_hid fp32 [H,H] -> packed f16 pairs for `recurrent`. (unchanged)
// Consumer thread (w=t>>6, l=t&63) covers h-slots i in [0,8): h = l + 64*i,
// k-slice of wave w: pairs kp = 32w + 4g + m (g in [0,8), m = dword in uint4).
//  - AGPR part (slots i<6):  uint4 idx ((w*6+i)*8+g)*64 + l   -> dwords [0, 98304)
//  - LDS part  (slots 6,7):  uint4 idx ((w*2+ii)*8+g)*64 + l  -> dwords [98304, 131072)
// ---------------------------------------------------------------------------
__global__ void wconv(const float* __restrict__ Whid,
                      unsigned* __restrict__ Wz) {
    int p = blockIdx.x * 256 + threadIdx.x;   // dword index, 0..131071
    int m  = p & 3;
    int u4 = p >> 2;
    int l, g, w, i;
    if (u4 < 24576) {                 // AGPR part
        l = u4 & 63; g = (u4 >> 6) & 7;
        int r = u4 >> 9;              // 0..47
        w = r / 6; i = r - 6 * w;
    } else {                          // LDS part
        int q = u4 - 24576;           // 0..8191
        l = q & 63; g = (q >> 6) & 7;
        int r = q >> 9;               // 0..15
        w = r >> 1; i = 6 + (r & 1);
    }
    int h  = l + 64 * i;
    int kp = 32 * w + 4 * g + m;
    float w0 = Whid[h * H_ + 2 * kp];
    float w1 = Whid[h * H_ + 2 * kp + 1];
    half2v hw = { (_Float16)w0, (_Float16)w1 };
    Wz[p] = __builtin_bit_cast(unsigned, hw);
}

// ---------------------------------------------------------------------------
// Kernel 2: v_in[b,t,h] = x[b,t,:] @ W_in[h,:] + b_in[h]  (unchanged)
// ---------------------------------------------------------------------------
__global__ __launch_bounds__(256) void vin_gemm(const float* __restrict__ x,
                                                const float* __restrict__ Win,
                                                const float* __restrict__ bin,
                                                float* __restrict__ vin) {
    __shared__ __align__(16) unsigned xs[64 * 64];   // 16 KB
    __shared__ __align__(16) unsigned ws[64 * 64];   // 16 KB
    const int tid = threadIdx.x;
    const int m0 = blockIdx.x * 64;
    const int n0 = blockIdx.y * 64;

    #pragma unroll
    for (int r = 0; r < 8; ++r) {
        int gi = r * 256 + tid;       // 0..2047
        int row = gi >> 5;            // 0..63
        int c4 = gi & 31;             // float4 index in the 128-float row
        float4 vx = ((const float4*)(x + (size_t)(m0 + row) * I_))[c4];
        float4 vw = ((const float4*)(Win + (size_t)(n0 + row) * I_))[c4];
        int sw = (row >> 2) & 15;
        int col = 4 * ((c4 >> 1) ^ sw) + (c4 & 1) * 2;  // swizzled dword col
        half2v x01 = { (_Float16)vx.x, (_Float16)vx.y };
        half2v x23 = { (_Float16)vx.z, (_Float16)vx.w };
        half2v w01 = { (_Float16)vw.x, (_Float16)vw.y };
        half2v w23 = { (_Float16)vw.z, (_Float16)vw.w };
        xs[row * 64 + col]     = __builtin_bit_cast(unsigned, x01);
        xs[row * 64 + col + 1] = __builtin_bit_cast(unsigned, x23);
        ws[row * 64 + col]     = __builtin_bit_cast(unsigned, w01);
        ws[row * 64 + col + 1] = __builtin_bit_cast(unsigned, w23);
    }
    __syncthreads();

    const int ty = tid >> 4, tx = tid & 15;
    float acc[4][4] = {};
    #pragma unroll
    for (int kb = 0; kb < 16; ++kb) {
        uint4 a4[4], b4[4];
        #pragma unroll
        for (int i = 0; i < 4; ++i)
            a4[i] = *(const uint4*)&xs[(ty * 4 + i) * 64 + 4 * (kb ^ ty)];
        #pragma unroll
        for (int j = 0; j < 4; ++j)
            b4[j] = *(const uint4*)&ws[(tx * 4 + j) * 64 + 4 * (kb ^ tx)];
        #pragma unroll
        for (int i = 0; i < 4; ++i)
            #pragma unroll
            for (int j = 0; j < 4; ++j) {
                acc[i][j] = dot2(a4[i].x, b4[j].x, acc[i][j]);
                acc[i][j] = dot2(a4[i].y, b4[j].y, acc[i][j]);
                acc[i][j] = dot2(a4[i].z, b4[j].z, acc[i][j]);
                acc[i][j] = dot2(a4[i].w, b4[j].w, acc[i][j]);
            }
    }

    float4 bv = ((const float4*)(bin + n0))[tx];
    #pragma unroll
    for (int i = 0; i < 4; ++i) {
        int m = m0 + ty * 4 + i;
        float4 o;
        o.x = acc[i][0] + bv.x; o.y = acc[i][1] + bv.y;
        o.z = acc[i][2] + bv.z; o.w = acc[i][3] + bv.w;
        ((float4*)(vin + (size_t)m * H_ + n0))[tx] = o;
    }
}

// ---------------------------------------------------------------------------
// Kernel 3: recurrence, one block per batch, k-split by wave.
// W residency, done explicitly this time:
//  - slots 0..5 (192 dwords/thread) parked in AGPRs via v_accvgpr_write at
//    init; fetched with volatile v_accvgpr_read (full-rate VALU) right
//    before each dot2.  LLVM's spill heuristic never sees a big array.
//    Budget: 192 acc + ~45 arch < 256 unified/wave at 2 waves/SIMD.
//  - slots 6,7 in LDS (128 KB), as before.
//  - stride-9 pbuf (odd stride -> 2 lanes/bank, free), tree reduce,
//    fr16 write before the fire-and-forget o-stores, lgkm-only barriers.
// ---------------------------------------------------------------------------
__global__ __launch_bounds__(512, 2)
__attribute__((amdgpu_waves_per_eu(2, 2)))
void recurrent(
        const uint4* __restrict__ Wz4,
        const float* __restrict__ vin,
        const float* __restrict__ init_state,
        const float* __restrict__ b_hid,
        const float* __restrict__ alpha,
        float* __restrict__ out0,
        float* __restrict__ out1) {
    __shared__ uint4 ldsW[8192];        // 128 KB : W slots 6,7
    __shared__ uint4 frbuf4[2][64];     //   2 KB : fr as f16 pairs, dbuf
    __shared__ float pbuf[8][576];      //  18 KB : partials [w][l*9+i]

    const int t = threadIdx.x;
    const int b = blockIdx.x;
    const int w = t >> 6, l = t & 63;

    // ---- W slots 0..5 into AGPRs: 48 coalesced uint4 loads, parked -------
    unsigned wa[6][8][4];
    const uint4* wp = Wz4 + (size_t)(w * 48) * 64 + l;
    #pragma unroll
    for (int i = 0; i < 6; ++i)
        #pragma unroll
        for (int g = 0; g < 8; ++g) {
            uint4 u = wp[(i * 8 + g) * 64];
            AWR(wa[i][g][0], u.x);
            AWR(wa[i][g][1], u.y);
            AWR(wa[i][g][2], u.z);
            AWR(wa[i][g][3], u.w);
        }

    // ---- W slots 6,7 into LDS: 16 b128 per thread, linear ----------------
    const uint4* lsrc = Wz4 + 24576;
    #pragma unroll
    for (int kk = 0; kk < 16; ++kk) ldsW[kk * 512 + t] = lsrc[kk * 512 + t];

    // ---- init ------------------------------------------------------------
    unsigned short* fr16 = (unsigned short*)frbuf4;   // [2][512]
    float v = init_state[b * H_ + t];
    fr16[t] = f32_to_f16b(fmaxf(v, 0.0f));
    const float bh = b_hid[t];
    const float al = alpha[t];
    const float om = 1.0f - al;

    const float* vinp = vin + (size_t)b * T_ * H_ + t;
    float* o0 = out0 + (size_t)b * T_ * H_ + t;
    float* o1 = out1 + (size_t)b * T_ * H_ + t;

    const int lw0 = (w * 2) * 8 * 64 + l;     // uint4 base, slot 6
    float* prow = &pbuf[w][l * 9];            // this thread's 8 partials

    __syncthreads();

    for (int s = 0; s < T_; ++s) {
        const int par = s & 1;
        float vinv = vinp[(size_t)s * H_];        // early issue, used late

        const uint4* fb = &frbuf4[par][w * 8];    // wave-uniform -> broadcast
        float a0 = 0.f, a1 = 0.f, a2 = 0.f, a3 = 0.f;
        float a4 = 0.f, a5 = 0.f, a6 = 0.f, a7 = 0.f;

        #pragma unroll
        for (int g = 0; g < 8; ++g) {
            uint4 wl0 = ldsW[lw0 + g * 64];       // lane-consecutive b128
            uint4 wl1 = ldsW[lw0 + 512 + g * 64];
            uint4 f = fb[g];                      // broadcast b128
            unsigned t0, t1, t2, t3;

            ARD(t0, wa[0][g][0]); ARD(t1, wa[0][g][1]);
            ARD(t2, wa[0][g][2]); ARD(t3, wa[0][g][3]);
            a0 = dot2(f.x, t0, a0); a0 = dot2(f.y, t1, a0);
            a0 = dot2(f.z, t2, a0); a0 = dot2(f.w, t3, a0);

            ARD(t0, wa[1][g][0]); ARD(t1, wa[1][g][1]);
            ARD(t2, wa[1][g][2]); ARD(t3, wa[1][g][3]);
            a1 = dot2(f.x, t0, a1); a1 = dot2(f.y, t1, a1);
            a1 = dot2(f.z, t2, a1); a1 = dot2(f.w, t3, a1);

            ARD(t0, wa[2][g][0]); ARD(t1, wa[2][g][1]);
            ARD(t2, wa[2][g][2]); ARD(t3, wa[2][g][3]);
            a2 = dot2(f.x, t0, a2); a2 = dot2(f.y, t1, a2);
            a2 = dot2(f.z, t2, a2); a2 = dot2(f.w, t3, a2);

            ARD(t0, wa[3][g][0]); ARD(t1, wa[3][g][1]);
            ARD(t2, wa[3][g][2]); ARD(t3, wa[3][g][3]);
            a3 = dot2(f.x, t0, a3); a3 = dot2(f.y, t1, a3);
            a3 = dot2(f.z, t2, a3); a3 = dot2(f.w, t3, a3);

            ARD(t0, wa[4][g][0]); ARD(t1, wa[4][g][1]);
            ARD(t2, wa[4][g][2]); ARD(t3, wa[4][g][3]);
            a4 = dot2(f.x, t0, a4); a4 = dot2(f.y, t1, a4);
            a4 = dot2(f.z, t2, a4); a4 = dot2(f.w, t3, a4);

            ARD(t0, wa[5][g][0]); ARD(t1, wa[5][g][1]);
            ARD(t2, wa[5][g][2]); ARD(t3, wa[5][g][3]);
            a5 = dot2(f.x, t0, a5); a5 = dot2(f.y, t1, a5);
            a5 = dot2(f.z, t2, a5); a5 = dot2(f.w, t3, a5);

            a6 = dot2(f.x, wl0.x, a6); a6 = dot2(f.y, wl0.y, a6);
            a6 = dot2(f.z, wl0.z, a6); a6 = dot2(f.w, wl0.w, a6);
            a7 = dot2(f.x, wl1.x, a7); a7 = dot2(f.y, wl1.y, a7);
            a7 = dot2(f.z, wl1.z, a7); a7 = dot2(f.w, wl1.w, a7);
        }

        // partial writes: 8 x b32, odd stride 9 -> 2 lanes/bank (free)
        prow[0] = a0; prow[1] = a1; prow[2] = a2; prow[3] = a3;
        prow[4] = a4; prow[5] = a5; prow[6] = a6; prow[7] = a7;

        // A: partials visible.  lgkm-only barrier -- no vmcnt drain.
        asm volatile("s_waitcnt lgkmcnt(0)" ::: "memory");
        __builtin_amdgcn_s_barrier();

        // reduction: thread t reduces h = t (hl = l, hi = w); tree adds
        float p0 = pbuf[0][l * 9 + w], p1 = pbuf[1][l * 9 + w];
        float p2 = pbuf[2][l * 9 + w], p3 = pbuf[3][l * 9 + w];
        float p4 = pbuf[4][l * 9 + w], p5 = pbuf[5][l * 9 + w];
        float p6 = pbuf[6][l * 9 + w], p7 = pbuf[7][l * 9 + w];
        float sum = ((p0 + p1) + (p2 + p3)) + ((p4 + p5) + (p6 + p7));

        float vhid = sum + bh;
        float vnew = om * v + al * (vhid + vinv);
        float frn = fmaxf(vnew, 0.0f);
        fr16[(par ^ 1) * 512 + t] = f32_to_f16b(frn);   // fr first: BAR-B gate
        float vr = om * vnew + al * vhid;
        v = vnew;
        float frr = fmaxf(vr, 0.0f);

        o0[(size_t)s * H_] = frn;                 // fire-and-forget
        o1[(size_t)s * H_] = frr;

        // B: fr complete + pbuf reads retired before next-step writes.
        asm volatile("s_waitcnt lgkmcnt(0)" ::: "memory");
        __builtin_amdgcn_s_barrier();
    }
}

// ---------------------------------------------------------------------------
extern "C" void kernel_launch(void* const* d_in, const int* in_sizes, int n_in,
                              void* d_out, int out_size, void* d_ws, size_t ws_size,
                              hipStream_t stream) {
    const float* x          = (const float*)d_in[0];
    const float* init_state = (const float*)d_in[1];
    const float* W_in       = (const float*)d_in[2];
    const float* b_in       = (const float*)d_in[3];
    const float* W_hid      = (const float*)d_in[4];
    const float* b_hid      = (const float*)d_in[5];
    const float* alpha      = (const float*)d_in[6];

    float* out0 = (float*)d_out;
    float* out1 = out0 + (size_t)B_ * T_ * H_;

    char* ws = (char*)d_ws;
    float*    vin = (float*)ws;                    // 67,108,864 B
    unsigned* Wz  = (unsigned*)(ws + 67108864);    //    524,288 B

    hipLaunchKernelGGL(wconv, dim3(512), dim3(256), 0, stream,
                       W_hid, Wz);
    hipLaunchKernelGGL(vin_gemm, dim3(512, 8), dim3(256), 0, stream,
                       x, W_in, b_in, vin);
    hipLaunchKernelGGL(recurrent, dim3(64), dim3(512), 0, stream,
                       (const uint4*)Wz, vin, init_state, b_hid, alpha,
                       out0, out1);
}

// Round 7
// 1034.736 us; speedup vs baseline: 15.1227x; 1.2442x over previous
//
#include <hip/hip_runtime.h>
#include <hip/hip_fp16.h>

#define B_ 64
#define T_ 512
#define I_ 128
#define H_ 512

typedef _Float16 half2v __attribute__((ext_vector_type(2)));
typedef _Float16 f16x8  __attribute__((ext_vector_type(8)));
typedef float    f32x4  __attribute__((ext_vector_type(4)));

__device__ __forceinline__ float dot2(unsigned a, unsigned b, float c) {
    return __builtin_amdgcn_fdot2(__builtin_bit_cast(half2v, a),
                                  __builtin_bit_cast(half2v, b), c, false);
}

__device__ __forceinline__ unsigned short f32_to_f16b(float f) {
    _Float16 h = (_Float16)f;
    return __builtin_bit_cast(unsigned short, h);
}

// Builtin MFMA: compiler handles ALL hazard wait-states and operand classes
// (B operand is av-class: reads pinned AGPRs directly, no moves).
#define MFMA(ACC, A, Bq) \
    ACC = __builtin_amdgcn_mfma_f32_16x16x32_f16((A), (Bq), (ACC), 0, 0, 0)

// ---------------------------------------------------------------------------
// Kernel 1: W_hid fp32 [H,H] -> f16 MFMA B-fragments.  (unchanged from R6)
// Fragment (w, kt, nt): lane l, elem j holds
//   B[k][n] = W_hid[n][k],  n = 64w + 16nt + (l&15),  k = 32kt + 8*(l>>4) + j
// stored at uint4 index ((w*16 + kt)*4 + nt)*64 + l  (dword m holds j=2m,2m+1).
// ---------------------------------------------------------------------------
__global__ void wconv(const float* __restrict__ Whid,
                      unsigned* __restrict__ Wz) {
    int p = blockIdx.x * 256 + threadIdx.x;   // dword index, 0..131071
    int m  = p & 3;
    int u4 = p >> 2;
    int l  = u4 & 63;
    int nt = (u4 >> 6) & 3;
    int kt = (u4 >> 8) & 15;
    int w  = (u4 >> 12) & 7;
    int h  = 64 * w + 16 * nt + (l & 15);     // n (output col) = h row of W_hid
    int k  = 32 * kt + 8 * (l >> 4) + 2 * m;
    float w0 = Whid[h * H_ + k];
    float w1 = Whid[h * H_ + k + 1];
    half2v hw = { (_Float16)w0, (_Float16)w1 };
    Wz[p] = __builtin_bit_cast(unsigned, hw);
}

// ---------------------------------------------------------------------------
// Kernel 2: v_in[b,t,h] = x[b,t,:] @ W_in[h,:] + b_in[h]  (unchanged)
// ---------------------------------------------------------------------------
__global__ __launch_bounds__(256) void vin_gemm(const float* __restrict__ x,
                                                const float* __restrict__ Win,
                                                const float* __restrict__ bin,
                                                float* __restrict__ vin) {
    __shared__ __align__(16) unsigned xs[64 * 64];   // 16 KB
    __shared__ __align__(16) unsigned ws[64 * 64];   // 16 KB
    const int tid = threadIdx.x;
    const int m0 = blockIdx.x * 64;
    const int n0 = blockIdx.y * 64;

    #pragma unroll
    for (int r = 0; r < 8; ++r) {
        int gi = r * 256 + tid;       // 0..2047
        int row = gi >> 5;            // 0..63
        int c4 = gi & 31;             // float4 index in the 128-float row
        float4 vx = ((const float4*)(x + (size_t)(m0 + row) * I_))[c4];
        float4 vw = ((const float4*)(Win + (size_t)(n0 + row) * I_))[c4];
        int sw = (row >> 2) & 15;
        int col = 4 * ((c4 >> 1) ^ sw) + (c4 & 1) * 2;  // swizzled dword col
        half2v x01 = { (_Float16)vx.x, (_Float16)vx.y };
        half2v x23 = { (_Float16)vx.z, (_Float16)vx.w };
        half2v w01 = { (_Float16)vw.x, (_Float16)vw.y };
        half2v w23 = { (_Float16)vw.z, (_Float16)vw.w };
        xs[row * 64 + col]     = __builtin_bit_cast(unsigned, x01);
        xs[row * 64 + col + 1] = __builtin_bit_cast(unsigned, x23);
        ws[row * 64 + col]     = __builtin_bit_cast(unsigned, w01);
        ws[row * 64 + col + 1] = __builtin_bit_cast(unsigned, w23);
    }
    __syncthreads();

    const int ty = tid >> 4, tx = tid & 15;
    float acc[4][4] = {};
    #pragma unroll
    for (int kb = 0; kb < 16; ++kb) {
        uint4 a4[4], b4[4];
        #pragma unroll
        for (int i = 0; i < 4; ++i)
            a4[i] = *(const uint4*)&xs[(ty * 4 + i) * 64 + 4 * (kb ^ ty)];
        #pragma unroll
        for (int j = 0; j < 4; ++j)
            b4[j] = *(const uint4*)&ws[(tx * 4 + j) * 64 + 4 * (kb ^ tx)];
        #pragma unroll
        for (int i = 0; i < 4; ++i)
            #pragma unroll
            for (int j = 0; j < 4; ++j) {
                acc[i][j] = dot2(a4[i].x, b4[j].x, acc[i][j]);
                acc[i][j] = dot2(a4[i].y, b4[j].y, acc[i][j]);
                acc[i][j] = dot2(a4[i].z, b4[j].z, acc[i][j]);
                acc[i][j] = dot2(a4[i].w, b4[j].w, acc[i][j]);
            }
    }

    float4 bv = ((const float4*)(bin + n0))[tx];
    #pragma unroll
    for (int i = 0; i < 4; ++i) {
        int m = m0 + ty * 4 + i;
        float4 o;
        o.x = acc[i][0] + bv.x; o.y = acc[i][1] + bv.y;
        o.z = acc[i][2] + bv.z; o.w = acc[i][3] + bv.w;
        ((float4*)(vin + (size_t)m * H_ + n0))[tx] = o;
    }
}

// ---------------------------------------------------------------------------
// Kernel 3: recurrence via MFMA (R6 structure, builtin MFMAs for hazard
// safety).  One block per batch, h-split by wave: wave w owns h in
// [64w, 64w+64) (4 N-tiles), full K=512 (16 K-tiles).
// A-fragment = fr replicated into all 16 rows (broadcast read from fr16
// LDS) -> every lane's C row holds the true result -> no cross-wave
// reduction; result for h = t selected in-lane by 3 cndmasks.
// B-fragments: kt 0..9 parked in AGPRs (MFMA reads AGPRs natively);
// kt 10..13 in LDS (128 KB); kt 14..15 re-read from L2 each step
// (laundered pointer, latency hidden under the MFMA chain).
// ONE lgkm-only barrier per step (fr double-buffer, no vmcnt drain).
// ---------------------------------------------------------------------------
__global__ __launch_bounds__(512, 2)
__attribute__((amdgpu_waves_per_eu(2, 2)))
void recurrent(
        const uint4* __restrict__ Wz4,
        const float* __restrict__ vin,
        const float* __restrict__ init_state,
        const float* __restrict__ b_hid,
        const float* __restrict__ alpha,
        float* __restrict__ out0,
        float* __restrict__ out1) {
    __shared__ uint4 ldsWb[8192];              // 128 KB : B-frags kt 10..13
    __shared__ unsigned short fr16[2][512];    //   2 KB : fr f16, dbuf

    const int t = threadIdx.x;
    const int b = blockIdx.x;
    const int w = t >> 6, l = t & 63;
    const int hi = l >> 4;                     // A k-group of this lane

    const uint4* wbase = Wz4 + (size_t)w * 4096 + l;

    // ---- park B-frags kt 0..9 in AGPRs (40 x 16B = 160 AGPRs) ------------
    f16x8 wb[10][4];
    #pragma unroll
    for (int kt = 0; kt < 10; ++kt)
        #pragma unroll
        for (int nt = 0; nt < 4; ++nt) {
            uint4 u = wbase[(kt * 4 + nt) * 64];
            wb[kt][nt] = __builtin_bit_cast(f16x8, u);
            asm("" : "+a"(wb[kt][nt]));        // force AGPR class at def
        }

    // ---- stage kt 10..13 into LDS: 16 uint4 per thread, coalesced --------
    #pragma unroll
    for (int i = 0; i < 16; ++i)
        ldsWb[w * 1024 + i * 64 + l] = wbase[2560 + i * 64];

    // ---- per-step L2-resident frags kt 14..15 (laundered base) -----------
    const uint4* gp = wbase + 3584;

    // ---- init ------------------------------------------------------------
    float v = init_state[b * H_ + t];
    fr16[0][t] = f32_to_f16b(fmaxf(v, 0.0f));
    const float bh = b_hid[t];
    const float al = alpha[t];
    const float om = 1.0f - al;
    const bool sel4 = (l & 16) != 0;
    const bool sel5 = (l & 32) != 0;

    const float* vinp = vin + (size_t)b * T_ * H_ + t;
    float* o0 = out0 + (size_t)b * T_ * H_ + t;
    float* o1 = out1 + (size_t)b * T_ * H_ + t;

    __syncthreads();

    for (int s = 0; s < T_; ++s) {
        const int par = s & 1;

        // issue the 8 L2 B-frag loads early; consumed at chain end
        asm volatile("" : "+v"(gp));           // defeat LICM: reload per step
        uint4 g0 = gp[0],   g1 = gp[64],  g2 = gp[128], g3 = gp[192];
        uint4 g4 = gp[256], g5 = gp[320], g6 = gp[384], g7 = gp[448];
        float vinv = vinp[(size_t)s * H_];     // early issue, used late

        f32x4 acc0 = {0.f, 0.f, 0.f, 0.f}, acc1 = {0.f, 0.f, 0.f, 0.f};
        f32x4 acc2 = {0.f, 0.f, 0.f, 0.f}, acc3 = {0.f, 0.f, 0.f, 0.f};

        // A-fragments: 16B broadcast per 16-lane group; rows replicated = fr
        const f16x8* frb =
            (const f16x8*)((const char*)&fr16[par][0] + hi * 16);

        #pragma unroll
        for (int kt = 0; kt < 10; ++kt) {
            f16x8 afr = frb[kt * 4];
            MFMA(acc0, afr, wb[kt][0]);
            MFMA(acc1, afr, wb[kt][1]);
            MFMA(acc2, afr, wb[kt][2]);
            MFMA(acc3, afr, wb[kt][3]);
        }
        #pragma unroll
        for (int kt = 10; kt < 14; ++kt) {
            f16x8 afr = frb[kt * 4];
            const f16x8* lb =
                (const f16x8*)&ldsWb[w * 1024 + (kt - 10) * 256 + l];
            MFMA(acc0, afr, lb[0]);
            MFMA(acc1, afr, lb[64]);
            MFMA(acc2, afr, lb[128]);
            MFMA(acc3, afr, lb[192]);
        }
        {
            f16x8 a14 = frb[14 * 4];
            MFMA(acc0, a14, __builtin_bit_cast(f16x8, g0));
            MFMA(acc1, a14, __builtin_bit_cast(f16x8, g1));
            MFMA(acc2, a14, __builtin_bit_cast(f16x8, g2));
            MFMA(acc3, a14, __builtin_bit_cast(f16x8, g3));
            f16x8 a15 = frb[15 * 4];
            MFMA(acc0, a15, __builtin_bit_cast(f16x8, g4));
            MFMA(acc1, a15, __builtin_bit_cast(f16x8, g5));
            MFMA(acc2, a15, __builtin_bit_cast(f16x8, g6));
            MFMA(acc3, a15, __builtin_bit_cast(f16x8, g7));
        }

        // lane l holds result for h = 64w + 16*nt + (l&15); pick nt = l>>4
        float s01 = sel4 ? acc1.x : acc0.x;
        float s23 = sel4 ? acc3.x : acc2.x;
        float vh  = sel5 ? s23 : s01;

        float vhid = vh + bh;
        float vnew = om * v + al * (vhid + vinv);
        float frn  = fmaxf(vnew, 0.0f);
        fr16[par ^ 1][t] = f32_to_f16b(frn);   // fr first: barrier gates this
        float vr = om * vnew + al * vhid;
        v = vnew;
        float frr = fmaxf(vr, 0.0f);
        o0[(size_t)s * H_] = frn;              // fire-and-forget
        o1[(size_t)s * H_] = frr;

        // fr visible to all waves; no vmcnt drain in the loop
        asm volatile("s_waitcnt lgkmcnt(0)" ::: "memory");
        __builtin_amdgcn_s_barrier();
    }
}

// ---------------------------------------------------------------------------
extern "C" void kernel_launch(void* const* d_in, const int* in_sizes, int n_in,
                              void* d_out, int out_size, void* d_ws, size_t ws_size,
                              hipStream_t stream) {
    const float* x          = (const float*)d_in[0];
    const float* init_state = (const float*)d_in[1];
    const float* W_in       = (const float*)d_in[2];
    const float* b_in       = (const float*)d_in[3];
    const float* W_hid      = (const float*)d_in[4];
    const float* b_hid      = (const float*)d_in[5];
    const float* alpha      = (const float*)d_in[6];

    float* out0 = (float*)d_out;
    float* out1 = out0 + (size_t)B_ * T_ * H_;

    char* ws = (char*)d_ws;
    float*    vin = (float*)ws;                    // 67,108,864 B
    unsigned* Wz  = (unsigned*)(ws + 67108864);    //    524,288 B

    hipLaunchKernelGGL(wconv, dim3(512), dim3(256), 0, stream,
                       W_hid, Wz);
    hipLaunchKernelGGL(vin_gemm, dim3(512, 8), dim3(256), 0, stream,
                       x, W_in, b_in, vin);
    hipLaunchKernelGGL(recurrent, dim3(64), dim3(512), 0, stream,
                       (const uint4*)Wz, vin, init_state, b_hid, alpha,
                       out0, out1);
}